// Round 6
// baseline (480.859 us; speedup 1.0000x reference)
//
#include <hip/hip_runtime.h>
#include <hip/hip_bf16.h>
#include <cstdint>
#include <cstddef>

#define N_NODES 100000
#define N_EDGES 3200000
#define IN_DIM  256
#define HID_DIM 64
#define OUT_DIM 32

#define NBINS      391        // ceil(100000/256), 256 nodes per bin
#define BIN_SHIFT  8
#define BIN_STRIDE 9216       // lambda=8192, +11 sigma headroom
#define BIN_EPB    8192

__device__ __forceinline__ int rfl(int x) { return __builtin_amdgcn_readfirstlane(x); }
__device__ __forceinline__ float rflf(int x) {
    return __uint_as_float((unsigned)__builtin_amdgcn_readfirstlane(x));
}

// ---------------- pass 1: bin edges by dst>>8, coalesced segment writes ----------------
__global__ __launch_bounds__(512)
void k_bin(const int* __restrict__ ei, int* __restrict__ bin_cursor,
           int2* __restrict__ binned) {
    __shared__ int  lcount[NBINS];
    __shared__ int  lstart[NBINS];
    __shared__ int  lplace[NBINS];
    __shared__ int  gbase[NBINS];
    __shared__ int  sc[512];
    __shared__ int2 stage[BIN_EPB];   // 64 KB

    const int tid  = threadIdx.x;
    const int e0   = blockIdx.x * BIN_EPB;
    const int nval = min(BIN_EPB, N_EDGES - e0);

    for (int i = tid; i < NBINS; i += 512) lcount[i] = 0;
    __syncthreads();

    #pragma unroll
    for (int k = 0; k < BIN_EPB / 512; ++k) {
        int e = e0 + k * 512 + tid;
        if (e < N_EDGES) atomicAdd(&lcount[ei[N_EDGES + e] >> BIN_SHIFT], 1);
    }
    __syncthreads();

    int v = (tid < NBINS) ? lcount[tid] : 0;
    sc[tid] = v; __syncthreads();
    for (int off = 1; off < 512; off <<= 1) {
        int x = sc[tid];
        if (tid >= off) x += sc[tid - off];
        __syncthreads(); sc[tid] = x; __syncthreads();
    }
    if (tid < NBINS) {
        int excl = sc[tid] - v;
        lstart[tid] = excl;
        lplace[tid] = excl;
        gbase[tid]  = atomicAdd(&bin_cursor[tid], v);
    }
    __syncthreads();

    #pragma unroll
    for (int k = 0; k < BIN_EPB / 512; ++k) {
        int e = e0 + k * 512 + tid;
        if (e < N_EDGES) {
            int s = ei[e];
            int d = ei[N_EDGES + e];
            int p = atomicAdd(&lplace[d >> BIN_SHIFT], 1);
            stage[p] = make_int2(s, d);
        }
    }
    __syncthreads();

    for (int i = tid; i < nval; i += 512) {
        int2 ed  = stage[i];
        int  b   = ed.y >> BIN_SHIFT;
        int  gix = gbase[b] + (i - lstart[b]);
        if (gix < BIN_STRIDE)
            binned[(size_t)b * BIN_STRIDE + gix] = ed;
    }
}

// ---------------- bin-count exclusive scan (1 block) ----------------
__global__ __launch_bounds__(512)
void k_binscan(const int* __restrict__ bin_cursor, int* __restrict__ bin_base,
               int* __restrict__ rowptr) {
    __shared__ int sc[512];
    int t = threadIdx.x;
    int v = (t < NBINS) ? min(bin_cursor[t], BIN_STRIDE) : 0;
    sc[t] = v; __syncthreads();
    for (int off = 1; off < 512; off <<= 1) {
        int x = sc[t];
        if (t >= off) x += sc[t - off];
        __syncthreads(); sc[t] = x; __syncthreads();
    }
    if (t < NBINS)      bin_base[t] = sc[t] - v;
    if (t == NBINS - 1) rowptr[N_NODES] = sc[t];
}

// ---------------- pass 2: per-bin LDS counting sort -> CSR (+dn) ----------------
__global__ __launch_bounds__(256)
void k_csr(const int2* __restrict__ binned, const int* __restrict__ bin_cursor,
           const int* __restrict__ bin_base, int* __restrict__ rowptr,
           float* __restrict__ dn, int2* __restrict__ csr2) {
    __shared__ int lcnt[256];
    __shared__ int lpl[256];
    __shared__ int sc[256];
    __shared__ int csr_s[BIN_STRIDE];   // 36.9 KB

    const int tid   = threadIdx.x;
    const int b     = blockIdx.x;
    const int n0    = b << BIN_SHIFT;
    const int cnt   = min(bin_cursor[b], BIN_STRIDE);
    const int ebase = bin_base[b];
    const int2* bb  = binned + (size_t)b * BIN_STRIDE;

    lcnt[tid] = 0;
    __syncthreads();
    for (int i = tid; i < cnt; i += 256)
        atomicAdd(&lcnt[bb[i].y & 255], 1);
    __syncthreads();

    int v = lcnt[tid];
    sc[tid] = v; __syncthreads();
    for (int off = 1; off < 256; off <<= 1) {
        int x = sc[tid];
        if (tid >= off) x += sc[tid - off];
        __syncthreads(); sc[tid] = x; __syncthreads();
    }
    int excl = sc[tid] - v;
    lpl[tid] = excl;
    int n = n0 + tid;
    if (n < N_NODES) {
        rowptr[n] = ebase + excl;
        dn[n]     = rsqrtf((float)v + 1.0f);   // +1 self-loop
    }
    __syncthreads();

    for (int i = tid; i < cnt; i += 256) {
        int2 ed = bb[i];
        int  p  = atomicAdd(&lpl[ed.y & 255], 1);
        csr_s[p] = ed.x;
    }
    __syncthreads();
    for (int i = tid; i < cnt; i += 256)
        csr2[ebase + i] = make_int2(csr_s[i], 0);   // .y filled by k_dnfill
}

// ---------------- pass 3: fill dn[src] bits into csr2.y ----------------
__global__ __launch_bounds__(256)
void k_dnfill(int2* __restrict__ csr2, const float* __restrict__ dn,
              const int* __restrict__ rowptr) {
    int i = blockIdx.x * blockDim.x + threadIdx.x;
    int total = rowptr[N_NODES];
    if (i < total) {
        int s = csr2[i].x;
        reinterpret_cast<int*>(csr2)[2 * i + 1] = __float_as_int(dn[s]);
    }
}

// ---------------- tiled fp32 GEMM: Y[M,NC] = X[M,KD] @ W[KD,NC] ----------------
template<int KD, int NC>
__global__ __launch_bounds__(32 * (NC / 8))
void k_gemm(const float* __restrict__ X, const float* __restrict__ W,
            float* __restrict__ Y, int M) {
    constexpr int TC = NC / 8;
    constexpr int THREADS = 32 * TC;
    constexpr int KC = 32;
    __shared__ float Xs[128][33];
    __shared__ float Ws[KC][NC];

    const int tid  = threadIdx.x;
    const int tr   = tid / TC;
    const int tc   = tid % TC;
    const int row0 = blockIdx.x * 128;

    float acc[4][8];
    #pragma unroll
    for (int i = 0; i < 4; ++i)
        #pragma unroll
        for (int j = 0; j < 8; ++j) acc[i][j] = 0.f;

    for (int kc = 0; kc < KD; kc += KC) {
        #pragma unroll
        for (int i = tid; i < 128 * (KC / 4); i += THREADS) {
            int r  = i / (KC / 4);
            int k4 = (i % (KC / 4)) * 4;
            float4 v = make_float4(0.f, 0.f, 0.f, 0.f);
            int gr = row0 + r;
            if (gr < M)
                v = *reinterpret_cast<const float4*>(&X[(size_t)gr * KD + kc + k4]);
            Xs[r][k4 + 0] = v.x; Xs[r][k4 + 1] = v.y;
            Xs[r][k4 + 2] = v.z; Xs[r][k4 + 3] = v.w;
        }
        #pragma unroll
        for (int i = tid; i < KC * (NC / 4); i += THREADS) {
            int kk = i / (NC / 4);
            int c4 = (i % (NC / 4)) * 4;
            *reinterpret_cast<float4*>(&Ws[kk][c4]) =
                *reinterpret_cast<const float4*>(&W[(size_t)(kc + kk) * NC + c4]);
        }
        __syncthreads();

        #pragma unroll
        for (int kk = 0; kk < KC; ++kk) {
            float xv[4];
            #pragma unroll
            for (int i = 0; i < 4; ++i) xv[i] = Xs[tr * 4 + i][kk];
            float4 w0 = *reinterpret_cast<const float4*>(&Ws[kk][tc * 8]);
            float4 w1 = *reinterpret_cast<const float4*>(&Ws[kk][tc * 8 + 4]);
            float wv[8] = {w0.x, w0.y, w0.z, w0.w, w1.x, w1.y, w1.z, w1.w};
            #pragma unroll
            for (int i = 0; i < 4; ++i)
                #pragma unroll
                for (int j = 0; j < 8; ++j)
                    acc[i][j] = fmaf(xv[i], wv[j], acc[i][j]);
        }
        __syncthreads();
    }

    #pragma unroll
    for (int i = 0; i < 4; ++i) {
        int gr = row0 + tr * 4 + i;
        if (gr < M) {
            float4 o0 = make_float4(acc[i][0], acc[i][1], acc[i][2], acc[i][3]);
            float4 o1 = make_float4(acc[i][4], acc[i][5], acc[i][6], acc[i][7]);
            *reinterpret_cast<float4*>(&Y[(size_t)gr * NC + tc * 8])     = o0;
            *reinterpret_cast<float4*>(&Y[(size_t)gr * NC + tc * 8 + 4]) = o1;
        }
    }
}

// ---------------- agg1 (+bias+relu) fused with GEMM2 -> H2 ----------------
// one wave per node; lane = feature. Scalarized edge loop: indices and
// coefficients are wave-uniform (SGPR via s_load/readfirstlane); vector pipe
// does 1 gather + 1 fma per edge. Summation order IDENTICAL to round-2/5:
// self-loop first, then edges ascending, single accumulator.
__global__ __launch_bounds__(256)
void k_agg1(const float* __restrict__ H1, const int* __restrict__ rowptr,
            const int2* __restrict__ csr2, const float* __restrict__ dn,
            const float* __restrict__ b1, const float* __restrict__ W2,
            float* __restrict__ H2) {
    __shared__ float W2s[HID_DIM * OUT_DIM];   // 8 KB
    for (int i = threadIdx.x; i < HID_DIM * OUT_DIM; i += 256) W2s[i] = W2[i];
    __syncthreads();

    int wid  = (blockIdx.x * blockDim.x + threadIdx.x) >> 6;
    int lane = threadIdx.x & 63;
    if (wid >= N_NODES) return;
    const int n = wid;

    const int base = rfl(rowptr[n]);
    const int cnt  = rfl(rowptr[n + 1]) - base;
    const float dnn = dn[n];

    float acc = dnn * H1[(size_t)n * HID_DIM + lane];   // self-loop first
    const int2* e2 = csr2 + base;
    #pragma unroll 4
    for (int j = 0; j < cnt; ++j) {
        int2 e = e2[j];                    // uniform address -> s_load
        int   sj  = rfl(e.x);
        float dsj = rflf(e.y);             // dn[src], precomputed
        acc = fmaf(dsj, H1[((size_t)sj * HID_DIM) + lane], acc);
    }
    float o = fmaxf(b1[lane] + dnn * acc, 0.f);   // out1 row, one per lane

    // fused GEMM2 (verbatim): H2[n][c] = sum_f o_f W2[f][c]
    const int c = lane & 31, h = lane >> 5;
    float acc2 = 0.f;
    #pragma unroll
    for (int fi = 0; fi < 32; ++fi) {
        int fg = h * 32 + fi;
        float vv = __shfl(o, fg);
        acc2 = fmaf(vv, W2s[fg * OUT_DIM + c], acc2);
    }
    acc2 += __shfl_xor(acc2, 32);
    if (h == 0) H2[(size_t)n * OUT_DIM + c] = acc2;
}

// ---------------- agg2 (+bias) fused with MLP head ----------------
// one wave per node; lane&31 = feature, halves take even/odd edges ascending
// (round-2/5 parity semantics, exact fma(0,.,acc) tail), then shfl_xor(32).
__global__ __launch_bounds__(256)
void k_agg2m(const float* __restrict__ H2, const int* __restrict__ rowptr,
             const int2* __restrict__ csr2, const float* __restrict__ dn,
             const float* __restrict__ b2, const float* __restrict__ Wp1,
             const float* __restrict__ bp1, const float* __restrict__ Wp2,
             const float* __restrict__ bp2, float* __restrict__ out_h,
             float* __restrict__ out_w) {
    __shared__ float Wp1s[OUT_DIM * HID_DIM];  // 8 KB
    __shared__ float Wp2s[HID_DIM];
    __shared__ float bp1s[HID_DIM];
    for (int i = threadIdx.x; i < OUT_DIM * HID_DIM; i += 256) Wp1s[i] = Wp1[i];
    if (threadIdx.x < HID_DIM) {
        Wp2s[threadIdx.x] = Wp2[threadIdx.x];
        bp1s[threadIdx.x] = bp1[threadIdx.x];
    }
    __syncthreads();

    int wid  = (blockIdx.x * blockDim.x + threadIdx.x) >> 6;
    int lane = threadIdx.x & 63;
    if (wid >= N_NODES) return;
    const int n = wid;

    const int base = rfl(rowptr[n]);
    const int cnt  = rfl(rowptr[n + 1]) - base;
    const float dnn = dn[n];
    const int f = lane & 31, h = lane >> 5;

    float acc = (h == 0) ? dnn * H2[(size_t)n * OUT_DIM + f] : 0.f;
    const int2* e2 = csr2 + base;
    #pragma unroll 2
    for (int j0 = 0; j0 < cnt; j0 += 2) {
        int2 ea = e2[j0];                  // uniform -> s_load
        int   s0 = rfl(ea.x);
        float d0 = rflf(ea.y);
        int   s1 = s0;
        float d1 = 0.f;                    // exact no-op for odd tail
        if (j0 + 1 < cnt) {                // wave-uniform branch
            int2 eb = e2[j0 + 1];
            s1 = rfl(eb.x);
            d1 = rflf(eb.y);
        }
        int   ss = (h == 0) ? s0 : s1;
        float dd = (h == 0) ? d0 : d1;
        acc = fmaf(dd, H2[((size_t)ss * OUT_DIM) + f], acc);
    }
    acc += __shfl_xor(acc, 32);                 // both halves hold full sum
    float hv = b2[f] + dnn * acc;               // h[n][f] on lane f and f+32
    if (h == 0) out_h[(size_t)n * OUT_DIM + f] = hv;

    // MLP (verbatim): p[j] = relu(bp1[j] + sum_f h_f Wp1[f][j])
    float p = bp1s[lane];
    #pragma unroll
    for (int ff = 0; ff < OUT_DIM; ++ff) {
        float hf = __shfl(hv, ff);
        p = fmaf(hf, Wp1s[ff * HID_DIM + lane], p);
    }
    p = fmaxf(p, 0.f);
    float z = p * Wp2s[lane];
    #pragma unroll
    for (int off = 32; off; off >>= 1) z += __shfl_xor(z, off);
    if (lane == 0) out_w[n] = 1.f / (1.f + __expf(-(z + bp2[0])));
}

// ---------------- launcher ----------------
extern "C" void kernel_launch(void* const* d_in, const int* in_sizes, int n_in,
                              void* d_out, int out_size, void* d_ws, size_t ws_size,
                              hipStream_t stream) {
    const float* x   = (const float*)d_in[0];
    const int*   ei  = (const int*)d_in[1];
    const float* W1  = (const float*)d_in[2];
    const float* b1  = (const float*)d_in[3];
    const float* W2  = (const float*)d_in[4];
    const float* b2  = (const float*)d_in[5];
    const float* Wp1 = (const float*)d_in[6];
    const float* bp1 = (const float*)d_in[7];
    const float* Wp2 = (const float*)d_in[8];
    const float* bp2 = (const float*)d_in[9];
    float* out = (float*)d_out;

    char* ws = (char*)d_ws;
    int*   bin_cursor = (int*)  (ws + 0);           //  1,564 B
    int*   bin_base   = (int*)  (ws + 2048);        //  1,564 B
    int*   rowptr     = (int*)  (ws + 4096);        //  400,004 B
    float* dn         = (float*)(ws + 404480);      //  400,000 B
    int2*  csr2       = (int2*) (ws + 804608);      //  25,600,000 B
    int2*  binned     = (int2*) (ws + 26404864);    //  28,827,648 B
    float* H1         = (float*)(ws + 55232512);    //  25,600,000 B
    float* H2         = (float*)(ws + 80832512);    //  12,800,000 B
    // end ~93.6 MB

    hipMemsetAsync(bin_cursor, 0, NBINS * sizeof(int), stream);

    k_bin<<<(N_EDGES + BIN_EPB - 1) / BIN_EPB, 512, 0, stream>>>(ei, bin_cursor, binned);
    k_binscan<<<1, 512, 0, stream>>>(bin_cursor, bin_base, rowptr);
    k_csr<<<NBINS, 256, 0, stream>>>(binned, bin_cursor, bin_base, rowptr, dn, csr2);
    k_dnfill<<<(N_EDGES + 255) / 256, 256, 0, stream>>>(csr2, dn, rowptr);

    k_gemm<IN_DIM, HID_DIM><<<(N_NODES + 127) / 128, 256, 0, stream>>>(x, W1, H1, N_NODES);

    k_agg1<<<(N_NODES + 3) / 4, 256, 0, stream>>>(H1, rowptr, csr2, dn, b1, W2, H2);
    k_agg2m<<<(N_NODES + 3) / 4, 256, 0, stream>>>(H2, rowptr, csr2, dn, b2,
                                                   Wp1, bp1, Wp2, bp2,
                                                   out, out + (size_t)N_NODES * OUT_DIM);
}

// Round 8
// 355.935 us; speedup vs baseline: 1.3510x; 1.3510x over previous
//
#include <hip/hip_runtime.h>
#include <hip/hip_bf16.h>
#include <cstdint>
#include <cstddef>

#define N_NODES 100000
#define N_EDGES 3200000
#define IN_DIM  256
#define HID_DIM 64
#define OUT_DIM 32

#define NBINS      391        // ceil(100000/256), 256 nodes per bin
#define BIN_SHIFT  8
#define BIN_STRIDE 9216       // lambda=8192, +11 sigma headroom
#define BIN_EPB    8192

typedef unsigned int uint;
typedef unsigned char uchar;

// ---- fused bin + gemm1 kernel: shared-LDS union layout (bytes) ----
// bin path:  lcount@0  lstart@1564  lplace@3128  gbase@4692  sc@6256
//            stage(uint[8192])@8304  binid(uchar[8192])@41072  -> 49264 B
// gemm path: Xs(float[2][128][33])@0 -> 33792  Ws(float[2][32][64])@33792 -> 50176 B
#define SMEM_BYTES 50176

__global__ __launch_bounds__(512)
void k_bin_gemm(const int* __restrict__ ei, int* __restrict__ bin_cursor,
                uint* __restrict__ binned, int* __restrict__ bin_base,
                int* __restrict__ rowptr,
                const float* __restrict__ X, const float* __restrict__ W,
                float* __restrict__ Y) {
    __shared__ __align__(16) char smem[SMEM_BYTES];
    const int bid = blockIdx.x;
    const int tid = threadIdx.x;

    if (bid < NBINS) {
        // ---------------- binning block ----------------
        int*   lcount = (int*)(smem);
        int*   lstart = (int*)(smem + 1564);
        int*   lplace = (int*)(smem + 3128);
        int*   gbase  = (int*)(smem + 4692);
        int*   sc     = (int*)(smem + 6256);
        uint*  stage  = (uint*)(smem + 8304);
        uchar* binid  = (uchar*)(smem + 41072);
        int*   done   = bin_cursor + NBINS;        // zeroed by memset

        const int e0   = bid * BIN_EPB;
        const int nval = min(BIN_EPB, N_EDGES - e0);

        for (int i = tid; i < NBINS; i += 512) lcount[i] = 0;
        __syncthreads();

        #pragma unroll
        for (int k = 0; k < BIN_EPB / 512; ++k) {
            int e = e0 + k * 512 + tid;
            if (e < N_EDGES) atomicAdd(&lcount[ei[N_EDGES + e] >> BIN_SHIFT], 1);
        }
        __syncthreads();

        int v = (tid < NBINS) ? lcount[tid] : 0;
        sc[tid] = v; __syncthreads();
        for (int off = 1; off < 512; off <<= 1) {
            int x = sc[tid];
            if (tid >= off) x += sc[tid - off];
            __syncthreads(); sc[tid] = x; __syncthreads();
        }
        if (tid < NBINS) {
            int excl = sc[tid] - v;
            lstart[tid] = excl;
            lplace[tid] = excl;
            gbase[tid]  = atomicAdd(&bin_cursor[tid], v);
        }
        __syncthreads();

        #pragma unroll
        for (int k = 0; k < BIN_EPB / 512; ++k) {
            int e = e0 + k * 512 + tid;
            if (e < N_EDGES) {
                int s = ei[e];
                int d = ei[N_EDGES + e];
                int b = d >> BIN_SHIFT;
                int p = atomicAdd(&lplace[b], 1);
                stage[p] = (uint)s | ((uint)(d & 255) << 17) | ((uint)(b >> 8) << 25);
                binid[p] = (uchar)(b & 255);
            }
        }
        __syncthreads();

        for (int i = tid; i < nval; i += 512) {
            uint ed = stage[i];
            int  b  = (int)binid[i] | (int)((ed >> 25) & 1u) << 8;
            int  gix = gbase[b] + (i - lstart[b]);
            if (gix < BIN_STRIDE)
                binned[(size_t)b * BIN_STRIDE + gix] = ed;
        }
        __syncthreads();

        // ---- last-block inline binscan ----
        if (tid == 0) {
            __threadfence();
            lcount[0] = (atomicAdd(done, 1) == NBINS - 1) ? 1 : 0;
        }
        __syncthreads();
        if (lcount[0]) {
            int t = tid;
            int vv = 0;
            if (t < NBINS) vv = min(atomicAdd(&bin_cursor[t], 0), BIN_STRIDE);
            sc[t] = vv; __syncthreads();
            for (int off = 1; off < 512; off <<= 1) {
                int x = sc[t];
                if (t >= off) x += sc[t - off];
                __syncthreads(); sc[t] = x; __syncthreads();
            }
            if (t < NBINS)      bin_base[t] = sc[t] - vv;
            if (t == NBINS - 1) rowptr[N_NODES] = sc[t];
        }
    } else {
        // ---------------- GEMM1 block: two 128-row tiles ----------------
        constexpr int KD = IN_DIM, NC = HID_DIM, KC = 32;
        const int half = tid >> 8;          // 0/1
        const int lt   = tid & 255;
        float* Xs = (float*)(smem) + half * 128 * 33;
        float* Ws = (float*)(smem + 33792) + half * KC * NC;
        const int tr   = lt / 8;
        const int tc   = lt % 8;
        const int row0 = ((bid - NBINS) * 2 + half) * 128;
        const int M    = N_NODES;

        float acc[4][8];
        #pragma unroll
        for (int i = 0; i < 4; ++i)
            #pragma unroll
            for (int j = 0; j < 8; ++j) acc[i][j] = 0.f;

        for (int kc = 0; kc < KD; kc += KC) {
            #pragma unroll
            for (int i = lt; i < 128 * (KC / 4); i += 256) {
                int r  = i / (KC / 4);
                int k4 = (i % (KC / 4)) * 4;
                float4 vv = make_float4(0.f, 0.f, 0.f, 0.f);
                int gr = row0 + r;
                if (gr < M)
                    vv = *reinterpret_cast<const float4*>(&X[(size_t)gr * KD + kc + k4]);
                Xs[r * 33 + k4 + 0] = vv.x; Xs[r * 33 + k4 + 1] = vv.y;
                Xs[r * 33 + k4 + 2] = vv.z; Xs[r * 33 + k4 + 3] = vv.w;
            }
            #pragma unroll
            for (int i = lt; i < KC * (NC / 4); i += 256) {
                int kk = i / (NC / 4);
                int c4 = (i % (NC / 4)) * 4;
                *reinterpret_cast<float4*>(&Ws[kk * NC + c4]) =
                    *reinterpret_cast<const float4*>(&W[(size_t)(kc + kk) * NC + c4]);
            }
            __syncthreads();

            #pragma unroll
            for (int kk = 0; kk < KC; ++kk) {
                float xv[4];
                #pragma unroll
                for (int i = 0; i < 4; ++i) xv[i] = Xs[(tr * 4 + i) * 33 + kk];
                float4 w0 = *reinterpret_cast<const float4*>(&Ws[kk * NC + tc * 8]);
                float4 w1 = *reinterpret_cast<const float4*>(&Ws[kk * NC + tc * 8 + 4]);
                float wv[8] = {w0.x, w0.y, w0.z, w0.w, w1.x, w1.y, w1.z, w1.w};
                #pragma unroll
                for (int i = 0; i < 4; ++i)
                    #pragma unroll
                    for (int j = 0; j < 8; ++j)
                        acc[i][j] = fmaf(xv[i], wv[j], acc[i][j]);
            }
            __syncthreads();
        }

        #pragma unroll
        for (int i = 0; i < 4; ++i) {
            int gr = row0 + tr * 4 + i;
            if (gr < M) {
                float4 o0 = make_float4(acc[i][0], acc[i][1], acc[i][2], acc[i][3]);
                float4 o1 = make_float4(acc[i][4], acc[i][5], acc[i][6], acc[i][7]);
                *reinterpret_cast<float4*>(&Y[(size_t)gr * NC + tc * 8])     = o0;
                *reinterpret_cast<float4*>(&Y[(size_t)gr * NC + tc * 8 + 4]) = o1;
            }
        }
    }
}

// ---------------- pass 2: per-bin LDS counting sort -> CSR (+dn) ----------------
__global__ __launch_bounds__(256)
void k_csr(const uint* __restrict__ binned, const int* __restrict__ bin_cursor,
           const int* __restrict__ bin_base, int* __restrict__ rowptr,
           float* __restrict__ dn, int* __restrict__ csr) {
    __shared__ int lcnt[256];
    __shared__ int lpl[256];
    __shared__ int sc[256];
    __shared__ int csr_s[BIN_STRIDE];   // 36.9 KB

    const int tid   = threadIdx.x;
    const int b     = blockIdx.x;
    const int n0    = b << BIN_SHIFT;
    const int cnt   = min(bin_cursor[b], BIN_STRIDE);
    const int ebase = bin_base[b];
    const uint* bb  = binned + (size_t)b * BIN_STRIDE;

    lcnt[tid] = 0;
    __syncthreads();
    for (int i = tid; i < cnt; i += 256)
        atomicAdd(&lcnt[(bb[i] >> 17) & 255u], 1);
    __syncthreads();

    int v = lcnt[tid];
    sc[tid] = v; __syncthreads();
    for (int off = 1; off < 256; off <<= 1) {
        int x = sc[tid];
        if (tid >= off) x += sc[tid - off];
        __syncthreads(); sc[tid] = x; __syncthreads();
    }
    int excl = sc[tid] - v;
    lpl[tid] = excl;
    int n = n0 + tid;
    if (n < N_NODES) {
        rowptr[n] = ebase + excl;
        dn[n]     = rsqrtf((float)v + 1.0f);   // +1 self-loop
    }
    __syncthreads();

    for (int i = tid; i < cnt; i += 256) {
        uint ed = bb[i];
        int  p  = atomicAdd(&lpl[(ed >> 17) & 255u], 1);
        csr_s[p] = (int)(ed & 0x1FFFFu);
    }
    __syncthreads();
    for (int i = tid; i < cnt; i += 256)
        csr[ebase + i] = csr_s[i];
}

// ---------------- agg1 (+bias+relu) fused with GEMM2 -> H2 ----------------
// one wave per node; lane = feature. Round-5 verbatim: single acc, self first,
// edges in CSR order, 8-deep batched loads; tails exact fma(0,v,acc).
__global__ __launch_bounds__(256)
void k_agg1(const float* __restrict__ H1, const int* __restrict__ rowptr,
            const int* __restrict__ csr, const float* __restrict__ dn,
            const float* __restrict__ b1, const float* __restrict__ W2,
            float* __restrict__ H2) {
    __shared__ float W2s[HID_DIM * OUT_DIM];   // 8 KB
    for (int i = threadIdx.x; i < HID_DIM * OUT_DIM; i += 256) W2s[i] = W2[i];
    __syncthreads();

    int wid  = (blockIdx.x * blockDim.x + threadIdx.x) >> 6;
    int lane = threadIdx.x & 63;
    if (wid >= N_NODES) return;
    const int n = wid;

    int rp = (lane < 2) ? rowptr[n + lane] : 0;
    int base = __shfl(rp, 0);
    int cnt  = __shfl(rp, 1) - base;
    const float dnn = dn[n];

    float acc = dnn * H1[(size_t)n * HID_DIM + lane];   // self-loop first
    for (int b0 = 0; b0 < cnt; b0 += 64) {
        int m = min(64, cnt - b0);
        int s = 0; float dsv = 0.f;
        if (lane < m) { s = csr[base + b0 + lane]; dsv = dn[s]; }
        for (int j0 = 0; j0 < m; j0 += 8) {
            float v[8], w[8];
            #pragma unroll
            for (int i = 0; i < 8; ++i) {
                int j  = j0 + i;
                int sj = __shfl(s, j);
                w[i] = __shfl(dsv, j);                 // 0 when j >= m
                v[i] = H1[(size_t)sj * HID_DIM + lane];
            }
            #pragma unroll
            for (int i = 0; i < 8; ++i) acc = fmaf(w[i], v[i], acc);
        }
    }
    float o = fmaxf(b1[lane] + dnn * acc, 0.f);   // out1 row, one per lane

    // fused GEMM2: H2[n][c] = sum_f o_f W2[f][c]
    const int c = lane & 31, h = lane >> 5;
    float acc2 = 0.f;
    #pragma unroll
    for (int fi = 0; fi < 32; ++fi) {
        int fg = h * 32 + fi;
        float vv = __shfl(o, fg);
        acc2 = fmaf(vv, W2s[fg * OUT_DIM + c], acc2);
    }
    acc2 += __shfl_xor(acc2, 32);
    if (h == 0) H2[(size_t)n * OUT_DIM + c] = acc2;
}

// ---------------- agg2 (+bias) fused with MLP head ----------------
// one wave per node; round-5 verbatim parity-split streams, 8-deep batching.
__global__ __launch_bounds__(256)
void k_agg2m(const float* __restrict__ H2, const int* __restrict__ rowptr,
             const int* __restrict__ csr, const float* __restrict__ dn,
             const float* __restrict__ b2, const float* __restrict__ Wp1,
             const float* __restrict__ bp1, const float* __restrict__ Wp2,
             const float* __restrict__ bp2, float* __restrict__ out_h,
             float* __restrict__ out_w) {
    __shared__ float Wp1s[OUT_DIM * HID_DIM];  // 8 KB
    __shared__ float Wp2s[HID_DIM];
    __shared__ float bp1s[HID_DIM];
    for (int i = threadIdx.x; i < OUT_DIM * HID_DIM; i += 256) Wp1s[i] = Wp1[i];
    if (threadIdx.x < HID_DIM) {
        Wp2s[threadIdx.x] = Wp2[threadIdx.x];
        bp1s[threadIdx.x] = bp1[threadIdx.x];
    }
    __syncthreads();

    int wid  = (blockIdx.x * blockDim.x + threadIdx.x) >> 6;
    int lane = threadIdx.x & 63;
    if (wid >= N_NODES) return;
    const int n = wid;

    int rp = (lane < 2) ? rowptr[n + lane] : 0;
    int base = __shfl(rp, 0);
    int cnt  = __shfl(rp, 1) - base;
    const float dnn = dn[n];
    const int f = lane & 31, h = lane >> 5;

    float acc = (h == 0) ? dnn * H2[(size_t)n * OUT_DIM + f] : 0.f;
    for (int b0 = 0; b0 < cnt; b0 += 64) {
        int m = min(64, cnt - b0);
        int s = 0; float dsv = 0.f;
        if (lane < m) { s = csr[base + b0 + lane]; dsv = dn[s]; }
        for (int j0 = h; j0 < m; j0 += 16) {
            float v[8], w[8];
            #pragma unroll
            for (int i = 0; i < 8; ++i) {
                int j  = j0 + 2 * i;
                int sj = __shfl(s, j);
                w[i] = __shfl(dsv, j);                 // 0 when j >= m
                v[i] = H2[(size_t)sj * OUT_DIM + f];
            }
            #pragma unroll
            for (int i = 0; i < 8; ++i) acc = fmaf(w[i], v[i], acc);
        }
    }
    acc += __shfl_xor(acc, 32);                 // both halves now hold full sum
    float hv = b2[f] + dnn * acc;               // h[n][f] on lane f and f+32
    if (h == 0) out_h[(size_t)n * OUT_DIM + f] = hv;

    // MLP: p[j] = relu(bp1[j] + sum_f h_f Wp1[f][j])
    float p = bp1s[lane];
    #pragma unroll
    for (int ff = 0; ff < OUT_DIM; ++ff) {
        float hf = __shfl(hv, ff);
        p = fmaf(hf, Wp1s[ff * HID_DIM + lane], p);
    }
    p = fmaxf(p, 0.f);
    float z = p * Wp2s[lane];
    #pragma unroll
    for (int off = 32; off; off >>= 1) z += __shfl_xor(z, off);
    if (lane == 0) out_w[n] = 1.f / (1.f + __expf(-(z + bp2[0])));
}

// ---------------- launcher ----------------
extern "C" void kernel_launch(void* const* d_in, const int* in_sizes, int n_in,
                              void* d_out, int out_size, void* d_ws, size_t ws_size,
                              hipStream_t stream) {
    const float* x   = (const float*)d_in[0];
    const int*   ei  = (const int*)d_in[1];
    const float* W1  = (const float*)d_in[2];
    const float* b1  = (const float*)d_in[3];
    const float* W2  = (const float*)d_in[4];
    const float* b2  = (const float*)d_in[5];
    const float* Wp1 = (const float*)d_in[6];
    const float* bp1 = (const float*)d_in[7];
    const float* Wp2 = (const float*)d_in[8];
    const float* bp2 = (const float*)d_in[9];
    float* out = (float*)d_out;

    char* ws = (char*)d_ws;
    // binned needs NBINS*BIN_STRIDE*4 = 391*9216*4 = 14,413,824 B (slot count,
    // NOT edge count — the round-7 failure was sizing this 12.8 MB and
    // overlapping H1).
    int*   bin_cursor = (int*)  (ws + 0);           //  1,568 B (incl. done ctr)
    int*   bin_base   = (int*)  (ws + 2048);        //  1,564 B
    int*   rowptr     = (int*)  (ws + 4096);        //  400,004 B
    float* dn         = (float*)(ws + 404480);      //  400,000 B
    int*   csr        = (int*)  (ws + 804608);      //  12,800,000 B
    uint*  binned     = (uint*) (ws + 13604608);    //  14,413,824 B -> ends 28,018,432
    float* H1         = (float*)(ws + 28018432);    //  25,600,000 B -> ends 53,618,432
    float* H2         = (float*)(ws + 53618432);    //  12,800,000 B -> ends 66,418,432
    // end ~66.4 MB

    hipMemsetAsync(bin_cursor, 0, (NBINS + 1) * sizeof(int), stream);

    // fused: binning (blocks 0..390, incl. inline binscan) + GEMM1 (blocks 391..781)
    k_bin_gemm<<<NBINS + 391, 512, 0, stream>>>(ei, bin_cursor, binned, bin_base,
                                                rowptr, x, W1, H1);
    k_csr<<<NBINS, 256, 0, stream>>>(binned, bin_cursor, bin_base, rowptr, dn, csr);

    k_agg1<<<(N_NODES + 3) / 4, 256, 0, stream>>>(H1, rowptr, csr, dn, b1, W2, H2);
    k_agg2m<<<(N_NODES + 3) / 4, 256, 0, stream>>>(H2, rowptr, csr, dn, b2,
                                                   Wp1, bp1, Wp2, bp2,
                                                   out, out + (size_t)N_NODES * OUT_DIM);
}

// Round 9
// 338.382 us; speedup vs baseline: 1.4211x; 1.0519x over previous
//
#include <hip/hip_runtime.h>
#include <hip/hip_bf16.h>
#include <cstdint>
#include <cstddef>

#define N_NODES 100000
#define N_EDGES 3200000
#define IN_DIM  256
#define HID_DIM 64
#define OUT_DIM 32

#define NBINS      391        // ceil(100000/256), 256 nodes per bin
#define BIN_SHIFT  8
#define BIN_STRIDE 9216       // lambda=8192, +11 sigma headroom
#define BIN_EPB    8192

typedef unsigned int uint;
typedef unsigned char uchar;

// ---- fused bin + gemm1 kernel: shared-LDS union layout (bytes) ----
#define SMEM_BYTES 50176

__global__ __launch_bounds__(512)
void k_bin_gemm(const int* __restrict__ ei, int* __restrict__ bin_cursor,
                uint* __restrict__ binned, int* __restrict__ bin_base,
                int* __restrict__ rowptr,
                const float* __restrict__ X, const float* __restrict__ W,
                float* __restrict__ Y) {
    __shared__ __align__(16) char smem[SMEM_BYTES];
    const int bid = blockIdx.x;
    const int tid = threadIdx.x;

    if (bid < NBINS) {
        // ---------------- binning block ----------------
        int*   lcount = (int*)(smem);
        int*   lstart = (int*)(smem + 1564);
        int*   lplace = (int*)(smem + 3128);
        int*   gbase  = (int*)(smem + 4692);
        int*   sc     = (int*)(smem + 6256);
        uint*  stage  = (uint*)(smem + 8304);
        uchar* binid  = (uchar*)(smem + 41072);
        int*   done   = bin_cursor + NBINS;        // zeroed by memset

        const int e0   = bid * BIN_EPB;
        const int nval = min(BIN_EPB, N_EDGES - e0);

        for (int i = tid; i < NBINS; i += 512) lcount[i] = 0;
        __syncthreads();

        #pragma unroll
        for (int k = 0; k < BIN_EPB / 512; ++k) {
            int e = e0 + k * 512 + tid;
            if (e < N_EDGES) atomicAdd(&lcount[ei[N_EDGES + e] >> BIN_SHIFT], 1);
        }
        __syncthreads();

        int v = (tid < NBINS) ? lcount[tid] : 0;
        sc[tid] = v; __syncthreads();
        for (int off = 1; off < 512; off <<= 1) {
            int x = sc[tid];
            if (tid >= off) x += sc[tid - off];
            __syncthreads(); sc[tid] = x; __syncthreads();
        }
        if (tid < NBINS) {
            int excl = sc[tid] - v;
            lstart[tid] = excl;
            lplace[tid] = excl;
            gbase[tid]  = atomicAdd(&bin_cursor[tid], v);
        }
        __syncthreads();

        #pragma unroll
        for (int k = 0; k < BIN_EPB / 512; ++k) {
            int e = e0 + k * 512 + tid;
            if (e < N_EDGES) {
                int s = ei[e];
                int d = ei[N_EDGES + e];
                int b = d >> BIN_SHIFT;
                int p = atomicAdd(&lplace[b], 1);
                stage[p] = (uint)s | ((uint)(d & 255) << 17) | ((uint)(b >> 8) << 25);
                binid[p] = (uchar)(b & 255);
            }
        }
        __syncthreads();

        for (int i = tid; i < nval; i += 512) {
            uint ed = stage[i];
            int  b  = (int)binid[i] | (int)((ed >> 25) & 1u) << 8;
            int  gix = gbase[b] + (i - lstart[b]);
            if (gix < BIN_STRIDE)
                binned[(size_t)b * BIN_STRIDE + gix] = ed;
        }
        __syncthreads();

        // ---- last-block inline binscan ----
        if (tid == 0) {
            __threadfence();
            lcount[0] = (atomicAdd(done, 1) == NBINS - 1) ? 1 : 0;
        }
        __syncthreads();
        if (lcount[0]) {
            int t = tid;
            int vv = 0;
            if (t < NBINS) vv = min(atomicAdd(&bin_cursor[t], 0), BIN_STRIDE);
            sc[t] = vv; __syncthreads();
            for (int off = 1; off < 512; off <<= 1) {
                int x = sc[t];
                if (t >= off) x += sc[t - off];
                __syncthreads(); sc[t] = x; __syncthreads();
            }
            if (t < NBINS)      bin_base[t] = sc[t] - vv;
            if (t == NBINS - 1) rowptr[N_NODES] = sc[t];
        }
    } else {
        // ---------------- GEMM1 block: two 128-row tiles ----------------
        constexpr int KD = IN_DIM, NC = HID_DIM, KC = 32;
        const int half = tid >> 8;          // 0/1
        const int lt   = tid & 255;
        float* Xs = (float*)(smem) + half * 128 * 33;
        float* Ws = (float*)(smem + 33792) + half * KC * NC;
        const int tr   = lt / 8;
        const int tc   = lt % 8;
        const int row0 = ((bid - NBINS) * 2 + half) * 128;
        const int M    = N_NODES;

        float acc[4][8];
        #pragma unroll
        for (int i = 0; i < 4; ++i)
            #pragma unroll
            for (int j = 0; j < 8; ++j) acc[i][j] = 0.f;

        for (int kc = 0; kc < KD; kc += KC) {
            #pragma unroll
            for (int i = lt; i < 128 * (KC / 4); i += 256) {
                int r  = i / (KC / 4);
                int k4 = (i % (KC / 4)) * 4;
                float4 vv = make_float4(0.f, 0.f, 0.f, 0.f);
                int gr = row0 + r;
                if (gr < M)
                    vv = *reinterpret_cast<const float4*>(&X[(size_t)gr * KD + kc + k4]);
                Xs[r * 33 + k4 + 0] = vv.x; Xs[r * 33 + k4 + 1] = vv.y;
                Xs[r * 33 + k4 + 2] = vv.z; Xs[r * 33 + k4 + 3] = vv.w;
            }
            #pragma unroll
            for (int i = lt; i < KC * (NC / 4); i += 256) {
                int kk = i / (NC / 4);
                int c4 = (i % (NC / 4)) * 4;
                *reinterpret_cast<float4*>(&Ws[kk * NC + c4]) =
                    *reinterpret_cast<const float4*>(&W[(size_t)(kc + kk) * NC + c4]);
            }
            __syncthreads();

            #pragma unroll
            for (int kk = 0; kk < KC; ++kk) {
                float xv[4];
                #pragma unroll
                for (int i = 0; i < 4; ++i) xv[i] = Xs[(tr * 4 + i) * 33 + kk];
                float4 w0 = *reinterpret_cast<const float4*>(&Ws[kk * NC + tc * 8]);
                float4 w1 = *reinterpret_cast<const float4*>(&Ws[kk * NC + tc * 8 + 4]);
                float wv[8] = {w0.x, w0.y, w0.z, w0.w, w1.x, w1.y, w1.z, w1.w};
                #pragma unroll
                for (int i = 0; i < 4; ++i)
                    #pragma unroll
                    for (int j = 0; j < 8; ++j)
                        acc[i][j] = fmaf(xv[i], wv[j], acc[i][j]);
            }
            __syncthreads();
        }

        #pragma unroll
        for (int i = 0; i < 4; ++i) {
            int gr = row0 + tr * 4 + i;
            if (gr < M) {
                float4 o0 = make_float4(acc[i][0], acc[i][1], acc[i][2], acc[i][3]);
                float4 o1 = make_float4(acc[i][4], acc[i][5], acc[i][6], acc[i][7]);
                *reinterpret_cast<float4*>(&Y[(size_t)gr * NC + tc * 8])     = o0;
                *reinterpret_cast<float4*>(&Y[(size_t)gr * NC + tc * 8 + 4]) = o1;
            }
        }
    }
}

// ---------------- pass 2: per-bin LDS counting sort -> CSR (+dn) ----------------
__global__ __launch_bounds__(256)
void k_csr(const uint* __restrict__ binned, const int* __restrict__ bin_cursor,
           const int* __restrict__ bin_base, int* __restrict__ rowptr,
           float* __restrict__ dn, int* __restrict__ csr) {
    __shared__ int lcnt[256];
    __shared__ int lpl[256];
    __shared__ int sc[256];
    __shared__ int csr_s[BIN_STRIDE];   // 36.9 KB

    const int tid   = threadIdx.x;
    const int b     = blockIdx.x;
    const int n0    = b << BIN_SHIFT;
    const int cnt   = min(bin_cursor[b], BIN_STRIDE);
    const int ebase = bin_base[b];
    const uint* bb  = binned + (size_t)b * BIN_STRIDE;

    lcnt[tid] = 0;
    __syncthreads();
    for (int i = tid; i < cnt; i += 256)
        atomicAdd(&lcnt[(bb[i] >> 17) & 255u], 1);
    __syncthreads();

    int v = lcnt[tid];
    sc[tid] = v; __syncthreads();
    for (int off = 1; off < 256; off <<= 1) {
        int x = sc[tid];
        if (tid >= off) x += sc[tid - off];
        __syncthreads(); sc[tid] = x; __syncthreads();
    }
    int excl = sc[tid] - v;
    lpl[tid] = excl;
    int n = n0 + tid;
    if (n < N_NODES) {
        rowptr[n] = ebase + excl;
        dn[n]     = rsqrtf((float)v + 1.0f);   // +1 self-loop
    }
    __syncthreads();

    for (int i = tid; i < cnt; i += 256) {
        uint ed = bb[i];
        int  p  = atomicAdd(&lpl[(ed >> 17) & 255u], 1);
        csr_s[p] = (int)(ed & 0x1FFFFu);
    }
    __syncthreads();
    for (int i = tid; i < cnt; i += 256)
        csr[ebase + i] = csr_s[i];
}

// ---------------- agg1 (+bias+relu) fused with GEMM2 -> H2 ----------------
// TWO nodes per wave: half = lane>>5 picks node, l = lane&31 = feature PAIR
// (float2 gathers). Per-feature FP chain is BIT-IDENTICAL to round-5/8:
// self-loop first, then that node's edges in CSR order, single accumulator;
// idle slots contribute exact fma(0,v,acc). One dwordx2 VMEM instr now
// serves 2 edges (one per half-wave).
__global__ __launch_bounds__(256)
void k_agg1(const float* __restrict__ H1, const int* __restrict__ rowptr,
            const int* __restrict__ csr, const float* __restrict__ dn,
            const float* __restrict__ b1, const float* __restrict__ W2,
            float* __restrict__ H2) {
    __shared__ float W2s[HID_DIM * OUT_DIM];   // 8 KB
    for (int i = threadIdx.x; i < HID_DIM * OUT_DIM; i += 256) W2s[i] = W2[i];
    __syncthreads();

    int wid  = (blockIdx.x * blockDim.x + threadIdx.x) >> 6;   // wave id
    int lane = threadIdx.x & 63;
    if (wid >= N_NODES / 2) return;            // N_NODES even
    const int half = lane >> 5;                // 0 -> node A, 1 -> node B
    const int hb   = half << 5;
    const int l    = lane & 31;                // feature pair index
    const int n    = 2 * wid + half;           // this half's node

    int rp = (l < 2) ? rowptr[n + l] : 0;      // lanes 0,1 (A) / 32,33 (B)
    int base = __shfl(rp, hb + 0);
    int cnt  = __shfl(rp, hb + 1) - base;
    const float dnn = dn[n];

    float2 self2 = *reinterpret_cast<const float2*>(H1 + (size_t)n * HID_DIM + 2 * l);
    float2 acc;
    acc.x = dnn * self2.x;                     // self-loop first (r5 order)
    acc.y = dnn * self2.y;

    const int cnt2 = max(cnt, __shfl_xor(cnt, 32));   // uniform loop bound
    for (int b0 = 0; b0 < cnt2; b0 += 32) {
        int m_own = min(32, cnt - b0);          // may be <= 0
        int m_max = min(32, cnt2 - b0);         // >= 1
        int s = 0; float dsv = 0.f;
        if (l < m_own) { s = csr[base + b0 + l]; dsv = dn[s]; }
        for (int j0 = 0; j0 < m_max; j0 += 8) {
            float2 v[8]; float w[8];
            #pragma unroll
            for (int i = 0; i < 8; ++i) {
                int j  = j0 + i;
                int sj = __shfl(s, hb + j);
                w[i] = __shfl(dsv, hb + j);     // 0 beyond own edge count
                v[i] = *reinterpret_cast<const float2*>(H1 + (size_t)sj * HID_DIM + 2 * l);
            }
            #pragma unroll
            for (int i = 0; i < 8; ++i) {
                acc.x = fmaf(w[i], v[i].x, acc.x);
                acc.y = fmaf(w[i], v[i].y, acc.y);
            }
        }
    }
    float2 b1q = *reinterpret_cast<const float2*>(b1 + 2 * l);
    float2 o;
    o.x = fmaxf(b1q.x + dnn * acc.x, 0.f);     // out1 features 2l, 2l+1
    o.y = fmaxf(b1q.y + dnn * acc.y, 0.f);

    // fused GEMM2, r5 association per node: acc2 = sum over f in [hh*32, hh*32+32)
    // ascending, then shfl_xor(32) combine. o_f lives at lane (nodebase + f/2),
    // component f&1.
    const int c = lane & 31, hh = lane >> 5;
    #pragma unroll
    for (int nodesel = 0; nodesel < 2; ++nodesel) {
        const int nb = nodesel << 5;           // source lane base for this node's o
        float acc2 = 0.f;
        #pragma unroll
        for (int fi = 0; fi < 32; ++fi) {
            int f = hh * 32 + fi;
            float vv = (f & 1) ? __shfl(o.y, nb + (f >> 1))
                               : __shfl(o.x, nb + (f >> 1));
            acc2 = fmaf(vv, W2s[f * OUT_DIM + c], acc2);
        }
        acc2 += __shfl_xor(acc2, 32);
        if (hh == 0) H2[(size_t)(2 * wid + nodesel) * OUT_DIM + c] = acc2;
    }
}

// ---------------- agg2 (+bias) fused with MLP head ----------------
// one wave per node; round-5/8 verbatim parity-split streams, 8-deep batching.
__global__ __launch_bounds__(256)
void k_agg2m(const float* __restrict__ H2, const int* __restrict__ rowptr,
             const int* __restrict__ csr, const float* __restrict__ dn,
             const float* __restrict__ b2, const float* __restrict__ Wp1,
             const float* __restrict__ bp1, const float* __restrict__ Wp2,
             const float* __restrict__ bp2, float* __restrict__ out_h,
             float* __restrict__ out_w) {
    __shared__ float Wp1s[OUT_DIM * HID_DIM];  // 8 KB
    __shared__ float Wp2s[HID_DIM];
    __shared__ float bp1s[HID_DIM];
    for (int i = threadIdx.x; i < OUT_DIM * HID_DIM; i += 256) Wp1s[i] = Wp1[i];
    if (threadIdx.x < HID_DIM) {
        Wp2s[threadIdx.x] = Wp2[threadIdx.x];
        bp1s[threadIdx.x] = bp1[threadIdx.x];
    }
    __syncthreads();

    int wid  = (blockIdx.x * blockDim.x + threadIdx.x) >> 6;
    int lane = threadIdx.x & 63;
    if (wid >= N_NODES) return;
    const int n = wid;

    int rp = (lane < 2) ? rowptr[n + lane] : 0;
    int base = __shfl(rp, 0);
    int cnt  = __shfl(rp, 1) - base;
    const float dnn = dn[n];
    const int f = lane & 31, h = lane >> 5;

    float acc = (h == 0) ? dnn * H2[(size_t)n * OUT_DIM + f] : 0.f;
    for (int b0 = 0; b0 < cnt; b0 += 64) {
        int m = min(64, cnt - b0);
        int s = 0; float dsv = 0.f;
        if (lane < m) { s = csr[base + b0 + lane]; dsv = dn[s]; }
        for (int j0 = h; j0 < m; j0 += 16) {
            float v[8], w[8];
            #pragma unroll
            for (int i = 0; i < 8; ++i) {
                int j  = j0 + 2 * i;
                int sj = __shfl(s, j);
                w[i] = __shfl(dsv, j);                 // 0 when j >= m
                v[i] = H2[(size_t)sj * OUT_DIM + f];
            }
            #pragma unroll
            for (int i = 0; i < 8; ++i) acc = fmaf(w[i], v[i], acc);
        }
    }
    acc += __shfl_xor(acc, 32);                 // both halves now hold full sum
    float hv = b2[f] + dnn * acc;               // h[n][f] on lane f and f+32
    if (h == 0) out_h[(size_t)n * OUT_DIM + f] = hv;

    // MLP: p[j] = relu(bp1[j] + sum_f h_f Wp1[f][j])
    float p = bp1s[lane];
    #pragma unroll
    for (int ff = 0; ff < OUT_DIM; ++ff) {
        float hf = __shfl(hv, ff);
        p = fmaf(hf, Wp1s[ff * HID_DIM + lane], p);
    }
    p = fmaxf(p, 0.f);
    float z = p * Wp2s[lane];
    #pragma unroll
    for (int off = 32; off; off >>= 1) z += __shfl_xor(z, off);
    if (lane == 0) out_w[n] = 1.f / (1.f + __expf(-(z + bp2[0])));
}

// ---------------- launcher ----------------
extern "C" void kernel_launch(void* const* d_in, const int* in_sizes, int n_in,
                              void* d_out, int out_size, void* d_ws, size_t ws_size,
                              hipStream_t stream) {
    const float* x   = (const float*)d_in[0];
    const int*   ei  = (const int*)d_in[1];
    const float* W1  = (const float*)d_in[2];
    const float* b1  = (const float*)d_in[3];
    const float* W2  = (const float*)d_in[4];
    const float* b2  = (const float*)d_in[5];
    const float* Wp1 = (const float*)d_in[6];
    const float* bp1 = (const float*)d_in[7];
    const float* Wp2 = (const float*)d_in[8];
    const float* bp2 = (const float*)d_in[9];
    float* out = (float*)d_out;

    char* ws = (char*)d_ws;
    // binned = NBINS*BIN_STRIDE*4 = 14,413,824 B (slot count, not edge count!)
    int*   bin_cursor = (int*)  (ws + 0);           //  1,568 B (incl. done ctr)
    int*   bin_base   = (int*)  (ws + 2048);        //  1,564 B
    int*   rowptr     = (int*)  (ws + 4096);        //  400,004 B
    float* dn         = (float*)(ws + 404480);      //  400,000 B
    int*   csr        = (int*)  (ws + 804608);      //  12,800,000 B
    uint*  binned     = (uint*) (ws + 13604608);    //  14,413,824 B -> ends 28,018,432
    float* H1         = (float*)(ws + 28018432);    //  25,600,000 B -> ends 53,618,432
    float* H2         = (float*)(ws + 53618432);    //  12,800,000 B -> ends 66,418,432

    hipMemsetAsync(bin_cursor, 0, (NBINS + 1) * sizeof(int), stream);

    // fused: binning (blocks 0..390, incl. inline binscan) + GEMM1 (blocks 391..781)
    k_bin_gemm<<<NBINS + 391, 512, 0, stream>>>(ei, bin_cursor, binned, bin_base,
                                                rowptr, x, W1, H1);
    k_csr<<<NBINS, 256, 0, stream>>>(binned, bin_cursor, bin_base, rowptr, dn, csr);

    // 2 nodes per wave -> N_NODES/2 waves
    k_agg1<<<(N_NODES / 2 + 3) / 4, 256, 0, stream>>>(H1, rowptr, csr, dn, b1, W2, H2);
    k_agg2m<<<(N_NODES + 3) / 4, 256, 0, stream>>>(H2, rowptr, csr, dn, b2,
                                                   Wp1, bp1, Wp2, bp2,
                                                   out, out + (size_t)N_NODES * OUT_DIM);
}

// Round 10
// 321.145 us; speedup vs baseline: 1.4973x; 1.0537x over previous
//
#include <hip/hip_runtime.h>
#include <hip/hip_bf16.h>
#include <cstdint>
#include <cstddef>

#define N_NODES 100000
#define N_EDGES 3200000
#define IN_DIM  256
#define HID_DIM 64
#define OUT_DIM 32

#define NBINS      391        // ceil(100000/256), 256 nodes per bin
#define BIN_SHIFT  8
#define BIN_STRIDE 9216       // lambda=8192, +11 sigma headroom
#define BIN_EPB    8192

typedef unsigned int uint;
typedef unsigned char uchar;

// ---------------- pass 1: bin edges by dst>>8 (packed uint), inline last-block scan ----------------
__global__ __launch_bounds__(512)
void k_bin(const int* __restrict__ ei, int* __restrict__ bin_cursor,
           uint* __restrict__ binned, int* __restrict__ bin_base,
           int* __restrict__ rowptr) {
    __shared__ int   lcount[NBINS];
    __shared__ int   lstart[NBINS];
    __shared__ int   lplace[NBINS];
    __shared__ int   gbase[NBINS];
    __shared__ int   sc[512];
    __shared__ uint  stage[BIN_EPB];    // 32 KB
    __shared__ uchar binid[BIN_EPB];    //  8 KB

    const int tid  = threadIdx.x;
    const int bid  = blockIdx.x;
    int*      done = bin_cursor + NBINS;   // zeroed by memset

    const int e0   = bid * BIN_EPB;
    const int nval = min(BIN_EPB, N_EDGES - e0);

    for (int i = tid; i < NBINS; i += 512) lcount[i] = 0;
    __syncthreads();

    #pragma unroll
    for (int k = 0; k < BIN_EPB / 512; ++k) {
        int e = e0 + k * 512 + tid;
        if (e < N_EDGES) atomicAdd(&lcount[ei[N_EDGES + e] >> BIN_SHIFT], 1);
    }
    __syncthreads();

    int v = (tid < NBINS) ? lcount[tid] : 0;
    sc[tid] = v; __syncthreads();
    for (int off = 1; off < 512; off <<= 1) {
        int x = sc[tid];
        if (tid >= off) x += sc[tid - off];
        __syncthreads(); sc[tid] = x; __syncthreads();
    }
    if (tid < NBINS) {
        int excl = sc[tid] - v;
        lstart[tid] = excl;
        lplace[tid] = excl;
        gbase[tid]  = atomicAdd(&bin_cursor[tid], v);
    }
    __syncthreads();

    #pragma unroll
    for (int k = 0; k < BIN_EPB / 512; ++k) {
        int e = e0 + k * 512 + tid;
        if (e < N_EDGES) {
            int s = ei[e];
            int d = ei[N_EDGES + e];
            int b = d >> BIN_SHIFT;
            int p = atomicAdd(&lplace[b], 1);
            stage[p] = (uint)s | ((uint)(d & 255) << 17) | ((uint)(b >> 8) << 25);
            binid[p] = (uchar)(b & 255);
        }
    }
    __syncthreads();

    for (int i = tid; i < nval; i += 512) {
        uint ed = stage[i];
        int  b  = (int)binid[i] | (int)((ed >> 25) & 1u) << 8;
        int  gix = gbase[b] + (i - lstart[b]);
        if (gix < BIN_STRIDE)
            binned[(size_t)b * BIN_STRIDE + gix] = ed;
    }
    __syncthreads();

    // ---- last-block inline binscan ----
    if (tid == 0) {
        __threadfence();
        lcount[0] = (atomicAdd(done, 1) == gridDim.x - 1) ? 1 : 0;
    }
    __syncthreads();
    if (lcount[0]) {
        int t = tid;
        int vv = 0;
        if (t < NBINS) vv = min(atomicAdd(&bin_cursor[t], 0), BIN_STRIDE);
        sc[t] = vv; __syncthreads();
        for (int off = 1; off < 512; off <<= 1) {
            int x = sc[t];
            if (t >= off) x += sc[t - off];
            __syncthreads(); sc[t] = x; __syncthreads();
        }
        if (t < NBINS)      bin_base[t] = sc[t] - vv;
        if (t == NBINS - 1) rowptr[N_NODES] = sc[t];
    }
}

// ---------------- tiled fp32 GEMM: Y[M,NC] = X[M,KD] @ W[KD,NC] ----------------
template<int KD, int NC>
__global__ __launch_bounds__(32 * (NC / 8))
void k_gemm(const float* __restrict__ X, const float* __restrict__ W,
            float* __restrict__ Y, int M) {
    constexpr int TC = NC / 8;
    constexpr int THREADS = 32 * TC;
    constexpr int KC = 32;
    __shared__ float Xs[128][33];
    __shared__ float Ws[KC][NC];

    const int tid  = threadIdx.x;
    const int tr   = tid / TC;
    const int tc   = tid % TC;
    const int row0 = blockIdx.x * 128;

    float acc[4][8];
    #pragma unroll
    for (int i = 0; i < 4; ++i)
        #pragma unroll
        for (int j = 0; j < 8; ++j) acc[i][j] = 0.f;

    for (int kc = 0; kc < KD; kc += KC) {
        #pragma unroll
        for (int i = tid; i < 128 * (KC / 4); i += THREADS) {
            int r  = i / (KC / 4);
            int k4 = (i % (KC / 4)) * 4;
            float4 v = make_float4(0.f, 0.f, 0.f, 0.f);
            int gr = row0 + r;
            if (gr < M)
                v = *reinterpret_cast<const float4*>(&X[(size_t)gr * KD + kc + k4]);
            Xs[r][k4 + 0] = v.x; Xs[r][k4 + 1] = v.y;
            Xs[r][k4 + 2] = v.z; Xs[r][k4 + 3] = v.w;
        }
        #pragma unroll
        for (int i = tid; i < KC * (NC / 4); i += THREADS) {
            int kk = i / (NC / 4);
            int c4 = (i % (NC / 4)) * 4;
            *reinterpret_cast<float4*>(&Ws[kk][c4]) =
                *reinterpret_cast<const float4*>(&W[(size_t)(kc + kk) * NC + c4]);
        }
        __syncthreads();

        #pragma unroll
        for (int kk = 0; kk < KC; ++kk) {
            float xv[4];
            #pragma unroll
            for (int i = 0; i < 4; ++i) xv[i] = Xs[tr * 4 + i][kk];
            float4 w0 = *reinterpret_cast<const float4*>(&Ws[kk][tc * 8]);
            float4 w1 = *reinterpret_cast<const float4*>(&Ws[kk][tc * 8 + 4]);
            float wv[8] = {w0.x, w0.y, w0.z, w0.w, w1.x, w1.y, w1.z, w1.w};
            #pragma unroll
            for (int i = 0; i < 4; ++i)
                #pragma unroll
                for (int j = 0; j < 8; ++j)
                    acc[i][j] = fmaf(xv[i], wv[j], acc[i][j]);
        }
        __syncthreads();
    }

    #pragma unroll
    for (int i = 0; i < 4; ++i) {
        int gr = row0 + tr * 4 + i;
        if (gr < M) {
            float4 o0 = make_float4(acc[i][0], acc[i][1], acc[i][2], acc[i][3]);
            float4 o1 = make_float4(acc[i][4], acc[i][5], acc[i][6], acc[i][7]);
            *reinterpret_cast<float4*>(&Y[(size_t)gr * NC + tc * 8])     = o0;
            *reinterpret_cast<float4*>(&Y[(size_t)gr * NC + tc * 8 + 4]) = o1;
        }
    }
}

// ---------------- pass 2: per-bin LDS counting sort -> CSR (+dn) ----------------
__global__ __launch_bounds__(256)
void k_csr(const uint* __restrict__ binned, const int* __restrict__ bin_cursor,
           const int* __restrict__ bin_base, int* __restrict__ rowptr,
           float* __restrict__ dn, int* __restrict__ csr) {
    __shared__ int lcnt[256];
    __shared__ int lpl[256];
    __shared__ int sc[256];
    __shared__ int csr_s[BIN_STRIDE];   // 36.9 KB

    const int tid   = threadIdx.x;
    const int b     = blockIdx.x;
    const int n0    = b << BIN_SHIFT;
    const int cnt   = min(bin_cursor[b], BIN_STRIDE);
    const int ebase = bin_base[b];
    const uint* bb  = binned + (size_t)b * BIN_STRIDE;

    lcnt[tid] = 0;
    __syncthreads();
    for (int i = tid; i < cnt; i += 256)
        atomicAdd(&lcnt[(bb[i] >> 17) & 255u], 1);
    __syncthreads();

    int v = lcnt[tid];
    sc[tid] = v; __syncthreads();
    for (int off = 1; off < 256; off <<= 1) {
        int x = sc[tid];
        if (tid >= off) x += sc[tid - off];
        __syncthreads(); sc[tid] = x; __syncthreads();
    }
    int excl = sc[tid] - v;
    lpl[tid] = excl;
    int n = n0 + tid;
    if (n < N_NODES) {
        rowptr[n] = ebase + excl;
        dn[n]     = rsqrtf((float)v + 1.0f);   // +1 self-loop
    }
    __syncthreads();

    for (int i = tid; i < cnt; i += 256) {
        uint ed = bb[i];
        int  p  = atomicAdd(&lpl[(ed >> 17) & 255u], 1);
        csr_s[p] = (int)(ed & 0x1FFFFu);
    }
    __syncthreads();
    for (int i = tid; i < cnt; i += 256)
        csr[ebase + i] = csr_s[i];
}

// ---------------- agg1 (+bias+relu) fused with GEMM2 -> H2 ----------------
// TWO nodes per wave (r9 verbatim, passing): half-wave per node, float2 gathers,
// per-feature FP chain bit-identical to round-5.
__global__ __launch_bounds__(256)
void k_agg1(const float* __restrict__ H1, const int* __restrict__ rowptr,
            const int* __restrict__ csr, const float* __restrict__ dn,
            const float* __restrict__ b1, const float* __restrict__ W2,
            float* __restrict__ H2) {
    __shared__ float W2s[HID_DIM * OUT_DIM];   // 8 KB
    for (int i = threadIdx.x; i < HID_DIM * OUT_DIM; i += 256) W2s[i] = W2[i];
    __syncthreads();

    int wid  = (blockIdx.x * blockDim.x + threadIdx.x) >> 6;
    int lane = threadIdx.x & 63;
    if (wid >= N_NODES / 2) return;
    const int half = lane >> 5;
    const int hb   = half << 5;
    const int l    = lane & 31;
    const int n    = 2 * wid + half;

    int rp = (l < 2) ? rowptr[n + l] : 0;
    int base = __shfl(rp, hb + 0);
    int cnt  = __shfl(rp, hb + 1) - base;
    const float dnn = dn[n];

    float2 self2 = *reinterpret_cast<const float2*>(H1 + (size_t)n * HID_DIM + 2 * l);
    float2 acc;
    acc.x = dnn * self2.x;
    acc.y = dnn * self2.y;

    const int cnt2 = max(cnt, __shfl_xor(cnt, 32));
    for (int b0 = 0; b0 < cnt2; b0 += 32) {
        int m_own = min(32, cnt - b0);
        int m_max = min(32, cnt2 - b0);
        int s = 0; float dsv = 0.f;
        if (l < m_own) { s = csr[base + b0 + l]; dsv = dn[s]; }
        for (int j0 = 0; j0 < m_max; j0 += 8) {
            float2 v[8]; float w[8];
            #pragma unroll
            for (int i = 0; i < 8; ++i) {
                int j  = j0 + i;
                int sj = __shfl(s, hb + j);
                w[i] = __shfl(dsv, hb + j);
                v[i] = *reinterpret_cast<const float2*>(H1 + (size_t)sj * HID_DIM + 2 * l);
            }
            #pragma unroll
            for (int i = 0; i < 8; ++i) {
                acc.x = fmaf(w[i], v[i].x, acc.x);
                acc.y = fmaf(w[i], v[i].y, acc.y);
            }
        }
    }
    float2 b1q = *reinterpret_cast<const float2*>(b1 + 2 * l);
    float2 o;
    o.x = fmaxf(b1q.x + dnn * acc.x, 0.f);
    o.y = fmaxf(b1q.y + dnn * acc.y, 0.f);

    const int c = lane & 31, hh = lane >> 5;
    #pragma unroll
    for (int nodesel = 0; nodesel < 2; ++nodesel) {
        const int nb = nodesel << 5;
        float acc2 = 0.f;
        #pragma unroll
        for (int fi = 0; fi < 32; ++fi) {
            int f = hh * 32 + fi;
            float vv = (f & 1) ? __shfl(o.y, nb + (f >> 1))
                               : __shfl(o.x, nb + (f >> 1));
            acc2 = fmaf(vv, W2s[f * OUT_DIM + c], acc2);
        }
        acc2 += __shfl_xor(acc2, 32);
        if (hh == 0) H2[(size_t)(2 * wid + nodesel) * OUT_DIM + c] = acc2;
    }
}

// ---------------- agg2 (+bias) fused with MLP head ----------------
// TWO nodes per wave: nd = lane>>5 node, h2 = (lane>>4)&1 parity stream,
// l = lane&15 feature pair (float2). Per-feature FP chain bit-identical to
// round-5: even stream = self + even edges ascending, odd stream = odd edges
// ascending, combine even+odd (shfl_xor 16); MLP ff-ascending; same 64-lane
// reduction tree. Tails exact fma(0,.,acc).
__global__ __launch_bounds__(256)
void k_agg2m(const float* __restrict__ H2, const int* __restrict__ rowptr,
             const int* __restrict__ csr, const float* __restrict__ dn,
             const float* __restrict__ b2, const float* __restrict__ Wp1,
             const float* __restrict__ bp1, const float* __restrict__ Wp2,
             const float* __restrict__ bp2, float* __restrict__ out_h,
             float* __restrict__ out_w) {
    __shared__ float Wp1s[OUT_DIM * HID_DIM];  // 8 KB
    __shared__ float Wp2s[HID_DIM];
    __shared__ float bp1s[HID_DIM];
    for (int i = threadIdx.x; i < OUT_DIM * HID_DIM; i += 256) Wp1s[i] = Wp1[i];
    if (threadIdx.x < HID_DIM) {
        Wp2s[threadIdx.x] = Wp2[threadIdx.x];
        bp1s[threadIdx.x] = bp1[threadIdx.x];
    }
    __syncthreads();

    int wid  = (blockIdx.x * blockDim.x + threadIdx.x) >> 6;
    int lane = threadIdx.x & 63;
    if (wid >= N_NODES / 2) return;
    const int nd  = lane >> 5;
    const int nb0 = nd << 5;
    const int l32 = lane & 31;
    const int l   = lane & 15;
    const int h2  = (lane >> 4) & 1;
    const int n   = 2 * wid + nd;

    int rp = (lane < 3) ? rowptr[2 * wid + lane] : 0;
    int base = __shfl(rp, nd);
    int cnt  = __shfl(rp, nd + 1) - base;
    const float dnn = dn[n];

    float2 self2 = *reinterpret_cast<const float2*>(H2 + (size_t)n * OUT_DIM + 2 * l);
    float2 acc;
    acc.x = (h2 == 0) ? dnn * self2.x : 0.f;
    acc.y = (h2 == 0) ? dnn * self2.y : 0.f;

    const int cnt2 = max(cnt, __shfl_xor(cnt, 32));
    for (int b0 = 0; b0 < cnt2; b0 += 32) {
        int m_own = min(32, cnt - b0);
        int m_max = min(32, cnt2 - b0);
        int s = 0; float dsv = 0.f;
        if (l32 < m_own) { s = csr[base + b0 + l32]; dsv = dn[s]; }
        for (int j0 = h2; j0 < m_max; j0 += 16) {
            float2 v[8]; float w[8];
            #pragma unroll
            for (int i = 0; i < 8; ++i) {
                int j  = j0 + 2 * i;              // <= j0+14 <= 31
                int sj = __shfl(s, nb0 + j);
                w[i] = __shfl(dsv, nb0 + j);      // 0 when j >= m_own
                v[i] = *reinterpret_cast<const float2*>(H2 + (size_t)sj * OUT_DIM + 2 * l);
            }
            #pragma unroll
            for (int i = 0; i < 8; ++i) {
                acc.x = fmaf(w[i], v[i].x, acc.x);
                acc.y = fmaf(w[i], v[i].y, acc.y);
            }
        }
    }
    acc.x += __shfl_xor(acc.x, 16);               // even + odd (r5 association)
    acc.y += __shfl_xor(acc.y, 16);
    float2 b2q = *reinterpret_cast<const float2*>(b2 + 2 * l);
    float2 hv;
    hv.x = b2q.x + dnn * acc.x;
    hv.y = b2q.y + dnn * acc.y;
    if (h2 == 0)
        *reinterpret_cast<float2*>(out_h + (size_t)n * OUT_DIM + 2 * l) = hv;

    // MLP head per node (all 64 lanes each): p[j]=relu(bp1[j]+sum_ff h_ff Wp1[ff][j])
    #pragma unroll
    for (int nodesel = 0; nodesel < 2; ++nodesel) {
        const int nb = nodesel << 5;              // h2==0 subgroup of that node
        float p = bp1s[lane];
        #pragma unroll
        for (int ff = 0; ff < OUT_DIM; ++ff) {
            float hf = (ff & 1) ? __shfl(hv.y, nb + (ff >> 1))
                                : __shfl(hv.x, nb + (ff >> 1));
            p = fmaf(hf, Wp1s[ff * HID_DIM + lane], p);
        }
        p = fmaxf(p, 0.f);
        float z = p * Wp2s[lane];
        #pragma unroll
        for (int off = 32; off; off >>= 1) z += __shfl_xor(z, off);
        if (lane == 0)
            out_w[2 * wid + nodesel] = 1.f / (1.f + __expf(-(z + bp2[0])));
    }
}

// ---------------- launcher ----------------
extern "C" void kernel_launch(void* const* d_in, const int* in_sizes, int n_in,
                              void* d_out, int out_size, void* d_ws, size_t ws_size,
                              hipStream_t stream) {
    const float* x   = (const float*)d_in[0];
    const int*   ei  = (const int*)d_in[1];
    const float* W1  = (const float*)d_in[2];
    const float* b1  = (const float*)d_in[3];
    const float* W2  = (const float*)d_in[4];
    const float* b2  = (const float*)d_in[5];
    const float* Wp1 = (const float*)d_in[6];
    const float* bp1 = (const float*)d_in[7];
    const float* Wp2 = (const float*)d_in[8];
    const float* bp2 = (const float*)d_in[9];
    float* out = (float*)d_out;

    char* ws = (char*)d_ws;
    // binned = NBINS*BIN_STRIDE*4 = 14,413,824 B (slot count, not edge count!)
    int*   bin_cursor = (int*)  (ws + 0);           //  1,568 B (incl. done ctr)
    int*   bin_base   = (int*)  (ws + 2048);        //  1,564 B
    int*   rowptr     = (int*)  (ws + 4096);        //  400,004 B
    float* dn         = (float*)(ws + 404480);      //  400,000 B
    int*   csr        = (int*)  (ws + 804608);      //  12,800,000 B
    uint*  binned     = (uint*) (ws + 13604608);    //  14,413,824 B -> ends 28,018,432
    float* H1         = (float*)(ws + 28018432);    //  25,600,000 B -> ends 53,618,432
    float* H2         = (float*)(ws + 53618432);    //  12,800,000 B -> ends 66,418,432

    hipMemsetAsync(bin_cursor, 0, (NBINS + 1) * sizeof(int), stream);

    k_bin<<<(N_EDGES + BIN_EPB - 1) / BIN_EPB, 512, 0, stream>>>(ei, bin_cursor, binned,
                                                                 bin_base, rowptr);
    k_gemm<IN_DIM, HID_DIM><<<(N_NODES + 127) / 128, 256, 0, stream>>>(x, W1, H1, N_NODES);
    k_csr<<<NBINS, 256, 0, stream>>>(binned, bin_cursor, bin_base, rowptr, dn, csr);

    k_agg1<<<(N_NODES / 2 + 3) / 4, 256, 0, stream>>>(H1, rowptr, csr, dn, b1, W2, H2);
    k_agg2m<<<(N_NODES / 2 + 3) / 4, 256, 0, stream>>>(H2, rowptr, csr, dn, b2,
                                                       Wp1, bp1, Wp2, bp2,
                                                       out, out + (size_t)N_NODES * OUT_DIM);
}